// Round 4
// baseline (1059.432 us; speedup 1.0000x reference)
//
#include <hip/hip_runtime.h>
#include <hip/hip_bf16.h>

typedef unsigned short u16;
typedef unsigned int   u32;

using frag_ab = __attribute__((ext_vector_type(8))) short;  // 8 bf16
using frag_cd = __attribute__((ext_vector_type(4))) float;  // 4 fp32

// ---------- bf16 helpers ----------
__device__ __forceinline__ float bf2f(u16 u) {
    union { u32 i; float f; } v; v.i = ((u32)u) << 16; return v.f;
}
__device__ __forceinline__ u16 f2bf(float f) {
    __hip_bfloat16 h = __float2bfloat16(f);
    u16 u; __builtin_memcpy(&u, &h, 2); return u;
}
__device__ __forceinline__ float lo2f(u32 u) { union { u32 i; float f; } v; v.i = u << 16; return v.f; }
__device__ __forceinline__ float hi2f(u32 u) { union { u32 i; float f; } v; v.i = u & 0xffff0000u; return v.f; }
__device__ __forceinline__ void unpack8(uint4 v, float* f) {
    f[0]=lo2f(v.x); f[1]=hi2f(v.x); f[2]=lo2f(v.y); f[3]=hi2f(v.y);
    f[4]=lo2f(v.z); f[5]=hi2f(v.z); f[6]=lo2f(v.w); f[7]=hi2f(v.w);
}
__device__ __forceinline__ void load4f(const u16* p, float* f) {
    ushort4 v = *reinterpret_cast<const ushort4*>(p);
    f[0]=bf2f(v.x); f[1]=bf2f(v.y); f[2]=bf2f(v.z); f[3]=bf2f(v.w);
}
__device__ __forceinline__ void store4bf(u16* p, const float* f) {
    ushort4 v; v.x=f2bf(f[0]); v.y=f2bf(f[1]); v.z=f2bf(f[2]); v.w=f2bf(f[3]);
    *reinterpret_cast<ushort4*>(p) = v;
}
__device__ __forceinline__ u32 pack2(float a, float b) {
    return (u32)f2bf(a) | ((u32)f2bf(b) << 16);
}

// async global->LDS DMA, 16B per lane; lds dest = wave-uniform base + lane*16
__device__ __forceinline__ void gld16(const u16* g, u16* l) {
    __builtin_amdgcn_global_load_lds(
        (const __attribute__((address_space(1))) u32*)g,
        (__attribute__((address_space(3))) u32*)l, 16, 0, 0);
}

// ---------- block reduction (256 threads = 4 waves) ----------
__device__ __forceinline__ void block_reduce2(float& s, float& ss, float* red) {
    #pragma unroll
    for (int off = 32; off > 0; off >>= 1) {
        s  += __shfl_down(s, off, 64);
        ss += __shfl_down(ss, off, 64);
    }
    int wv = threadIdx.x >> 6, ln = threadIdx.x & 63;
    if (ln == 0) { red[wv*2] = s; red[wv*2+1] = ss; }
    __syncthreads();
    s  = red[0] + red[2] + red[4] + red[6];
    ss = red[1] + red[3] + red[5] + red[7];
    __syncthreads();
}

// ---------- fp32 -> bf16 conversion (n4 = n/4 float4 groups) ----------
__global__ __launch_bounds__(256) void convert_kernel(
    const float* __restrict__ in, u16* __restrict__ out, int n4)
{
    int i = blockIdx.x * 256 + threadIdx.x;
    if (i < n4) {
        float4 v = reinterpret_cast<const float4*>(in)[i];
        ushort4 o; o.x=f2bf(v.x); o.y=f2bf(v.y); o.z=f2bf(v.z); o.w=f2bf(v.w);
        reinterpret_cast<ushort4*>(out)[i] = o;
    }
}

// ---------- pad concat(theta,mag) -> Abuf (64 x 1056 bf16) ----------
__global__ __launch_bounds__(256) void apad_kernel(
    const float* __restrict__ gth, const float* __restrict__ gmag,
    u16* __restrict__ Abuf)
{
    const int r = blockIdx.x;             // 0..63
    const int tid = threadIdx.x;
    for (int c0 = tid*4; c0 < 1056; c0 += 1024) {
        float f[4];
        #pragma unroll
        for (int i = 0; i < 4; ++i) {
            int c = c0 + i;
            f[i] = (c < 1024) ? gth[(size_t)r*1024 + c] : (c == 1024 ? gmag[r] : 0.f);
        }
        store4bf(Abuf + (size_t)r*1056 + c0, f);
    }
}

// ---------- pad up_W (2048 x 1025 fp32) -> Bbuf (2048 x 1056 bf16) ----------
__global__ __launch_bounds__(256) void wpad_kernel(
    const float* __restrict__ upW, u16* __restrict__ Bbuf)
{
    const int r = blockIdx.x;             // 0..2047
    const int tid = threadIdx.x;
    for (int c0 = tid*4; c0 < 1056; c0 += 1024) {
        float f[4];
        #pragma unroll
        for (int i = 0; i < 4; ++i) {
            int c = c0 + i;
            f[i] = (c < 1025) ? upW[(size_t)r*1025 + c] : 0.f;
        }
        store4bf(Bbuf + (size_t)r*1056 + c0, f);
    }
}

// ---------- setup: cos/sin tables ----------
__global__ __launch_bounds__(256) void setup_kernel(
    const float* __restrict__ sheaf_th, const float* __restrict__ gth,
    const float* __restrict__ gmag, const float* __restrict__ gwts,
    const float* __restrict__ strength, float* __restrict__ sheaf_cs,
    float* __restrict__ gist_cs)
{
    int bx = blockIdx.x, tid = threadIdx.x;
    if (bx < 4) {
        for (int j = tid; j < 1024; j += 256) {
            float th = sheaf_th[bx*1024 + j];
            sheaf_cs[bx*1024 + j]        = cosf(th);
            sheaf_cs[4096 + bx*1024 + j] = sinf(th);
        }
    } else {
        int b = bx - 4;
        float w[16], wsum = 0.f;
        #pragma unroll
        for (int k = 0; k < 16; ++k) {
            w[k] = gwts[b*16+k] * gmag[b*16+k];
            wsum += w[k];
        }
        float inv = 1.f / (wsum + 1e-8f);
        float sig = 1.f / (1.f + expf(-strength[0]));
        for (int j = tid; j < 1024; j += 256) {
            float th = 0.f;
            #pragma unroll
            for (int k = 0; k < 16; ++k)
                th += w[k] * inv * gth[(size_t)(b*16+k)*1024 + j];
            th *= sig;
            gist_cs[b*1024 + j]        = cosf(th);
            gist_cs[4096 + b*1024 + j] = sinf(th);
        }
    }
}

// ---------- LN over rows of 2048: fp32 in -> bf16 out ----------
__global__ __launch_bounds__(256) void ln_kernel(
    const float* __restrict__ in, const float* __restrict__ w,
    const float* __restrict__ b, u16* __restrict__ out)
{
    __shared__ float red[8];
    const size_t base = (size_t)blockIdx.x * 2048;
    const int e0 = threadIdx.x * 8;
    float x[8];
    *reinterpret_cast<float4*>(&x[0]) = *reinterpret_cast<const float4*>(in + base + e0);
    *reinterpret_cast<float4*>(&x[4]) = *reinterpret_cast<const float4*>(in + base + e0 + 4);
    float s = 0.f, ss = 0.f;
    #pragma unroll
    for (int i = 0; i < 8; ++i) { s += x[i]; ss += x[i]*x[i]; }
    block_reduce2(s, ss, red);
    const float mu = s * (1.f/2048.f);
    const float rin = rsqrtf(ss * (1.f/2048.f) - mu*mu + 1e-5f);
    float wv[8], bv[8];
    *reinterpret_cast<float4*>(&wv[0]) = *reinterpret_cast<const float4*>(w + e0);
    *reinterpret_cast<float4*>(&wv[4]) = *reinterpret_cast<const float4*>(w + e0 + 4);
    *reinterpret_cast<float4*>(&bv[0]) = *reinterpret_cast<const float4*>(b + e0);
    *reinterpret_cast<float4*>(&bv[4]) = *reinterpret_cast<const float4*>(b + e0 + 4);
    float o[8];
    #pragma unroll
    for (int i = 0; i < 8; ++i) o[i] = (x[i]-mu)*rin*wv[i] + bv[i];
    uint4 st = { pack2(o[0],o[1]), pack2(o[2],o[3]), pack2(o[4],o[5]), pack2(o[6],o[7]) };
    *reinterpret_cast<uint4*>(out + base + e0) = st;
}

// ---------- sheaf: pre = x1 - |alpha| * (4*x1 - sum rot_inv(shift(x1))) ----------
__global__ __launch_bounds__(256) void sheaf_kernel(
    const u16* __restrict__ x1, const float* __restrict__ scs,
    const float* __restrict__ alpha_p, u16* __restrict__ pre)
{
    const int row = blockIdx.x;
    const int t = row & 2047;
    const int j0 = threadIdx.x * 4;
    const size_t base = (size_t)row * 2048;
    const float a = fabsf(alpha_p[0]);

    float xr[4], xi[4];
    load4f(x1 + base + j0, xr);
    load4f(x1 + base + 1024 + j0, xi);
    float lr[4], li[4];
    #pragma unroll
    for (int m = 0; m < 4; ++m) { lr[m] = 4.f*xr[m]; li[m] = 4.f*xi[m]; }

    #pragma unroll
    for (int idx = 0; idx < 4; ++idx) {
        const int sh = 3 - idx;
        if (t >= sh) {
            const float4 c4 = *reinterpret_cast<const float4*>(&scs[idx*1024 + j0]);
            const float4 s4 = *reinterpret_cast<const float4*>(&scs[4096 + idx*1024 + j0]);
            float c[4] = {c4.x, c4.y, c4.z, c4.w};
            float sn[4] = {s4.x, s4.y, s4.z, s4.w};
            float yr[4], yi[4];
            load4f(x1 + base - (size_t)sh*2048 + j0, yr);
            load4f(x1 + base - (size_t)sh*2048 + 1024 + j0, yi);
            #pragma unroll
            for (int m = 0; m < 4; ++m) {
                lr[m] -= yr[m]*c[m] + yi[m]*sn[m];     // rot_inv real
                li[m] -= yi[m]*c[m] - yr[m]*sn[m];     // rot_inv imag
            }
        }
    }
    float pr[4], pi[4];
    #pragma unroll
    for (int m = 0; m < 4; ++m) { pr[m] = xr[m] - a*lr[m]; pi[m] = xi[m] - a*li[m]; }
    store4bf(pre + base + j0, pr);
    store4bf(pre + base + 1024 + j0, pi);
}

// ---------- stage2: xn=LN(xA); g=LN(rot(xn)); xB=xA-xn+g; x2=LN(xB) ----------
__global__ __launch_bounds__(256) void stage2_kernel(
    const u16* __restrict__ xA, const float* __restrict__ gcs,
    const float* __restrict__ lgw, const float* __restrict__ lgb,
    const float* __restrict__ grw, const float* __restrict__ grb,
    const float* __restrict__ gcaw, const float* __restrict__ gcab,
    u16* __restrict__ xB, u16* __restrict__ x2)
{
    __shared__ float red[8];
    const int row = blockIdx.x;
    const int b = row >> 11;
    const int j0 = threadIdx.x * 4;
    const size_t base = (size_t)row * 2048;

    float ar[4], ai[4];
    load4f(xA + base + j0, ar);
    load4f(xA + base + 1024 + j0, ai);

    float s = 0.f, ss = 0.f;
    #pragma unroll
    for (int m = 0; m < 4; ++m) { s += ar[m]+ai[m]; ss += ar[m]*ar[m] + ai[m]*ai[m]; }
    block_reduce2(s, ss, red);
    float mu = s * (1.f/2048.f);
    float rin = rsqrtf(ss * (1.f/2048.f) - mu*mu + 1e-5f);

    float w0[4], b0[4], w1[4], b1[4];
    *reinterpret_cast<float4*>(w0) = *reinterpret_cast<const float4*>(lgw + j0);
    *reinterpret_cast<float4*>(b0) = *reinterpret_cast<const float4*>(lgb + j0);
    *reinterpret_cast<float4*>(w1) = *reinterpret_cast<const float4*>(lgw + 1024 + j0);
    *reinterpret_cast<float4*>(b1) = *reinterpret_cast<const float4*>(lgb + 1024 + j0);
    float xnr[4], xni[4];
    #pragma unroll
    for (int m = 0; m < 4; ++m) {
        xnr[m] = (ar[m]-mu)*rin*w0[m] + b0[m];
        xni[m] = (ai[m]-mu)*rin*w1[m] + b1[m];
    }

    const float4 c4 = *reinterpret_cast<const float4*>(&gcs[b*1024 + j0]);
    const float4 s4 = *reinterpret_cast<const float4*>(&gcs[4096 + b*1024 + j0]);
    float c[4] = {c4.x, c4.y, c4.z, c4.w};
    float sn[4] = {s4.x, s4.y, s4.z, s4.w};
    float rr[4], ri[4];
    #pragma unroll
    for (int m = 0; m < 4; ++m) {
        rr[m] = xnr[m]*c[m] - xni[m]*sn[m];
        ri[m] = xnr[m]*sn[m] + xni[m]*c[m];
    }

    s = 0.f; ss = 0.f;
    #pragma unroll
    for (int m = 0; m < 4; ++m) { s += rr[m]+ri[m]; ss += rr[m]*rr[m] + ri[m]*ri[m]; }
    block_reduce2(s, ss, red);
    float mu2 = s * (1.f/2048.f);
    float rin2 = rsqrtf(ss * (1.f/2048.f) - mu2*mu2 + 1e-5f);

    *reinterpret_cast<float4*>(w0) = *reinterpret_cast<const float4*>(grw + j0);
    *reinterpret_cast<float4*>(b0) = *reinterpret_cast<const float4*>(grb + j0);
    *reinterpret_cast<float4*>(w1) = *reinterpret_cast<const float4*>(grw + 1024 + j0);
    *reinterpret_cast<float4*>(b1) = *reinterpret_cast<const float4*>(grb + 1024 + j0);
    float br[4], bi[4];
    #pragma unroll
    for (int m = 0; m < 4; ++m) {
        float gr_ = (rr[m]-mu2)*rin2*w0[m] + b0[m];
        float gi_ = (ri[m]-mu2)*rin2*w1[m] + b1[m];
        br[m] = ar[m] - xnr[m] + gr_;
        bi[m] = ai[m] - xni[m] + gi_;
    }
    store4bf(xB + base + j0, br);
    store4bf(xB + base + 1024 + j0, bi);

    s = 0.f; ss = 0.f;
    #pragma unroll
    for (int m = 0; m < 4; ++m) { s += br[m]+bi[m]; ss += br[m]*br[m] + bi[m]*bi[m]; }
    block_reduce2(s, ss, red);
    float mu3 = s * (1.f/2048.f);
    float rin3 = rsqrtf(ss * (1.f/2048.f) - mu3*mu3 + 1e-5f);

    *reinterpret_cast<float4*>(w0) = *reinterpret_cast<const float4*>(gcaw + j0);
    *reinterpret_cast<float4*>(b0) = *reinterpret_cast<const float4*>(gcab + j0);
    *reinterpret_cast<float4*>(w1) = *reinterpret_cast<const float4*>(gcaw + 1024 + j0);
    *reinterpret_cast<float4*>(b1) = *reinterpret_cast<const float4*>(gcab + 1024 + j0);
    float o0[4], o1[4];
    #pragma unroll
    for (int m = 0; m < 4; ++m) {
        o0[m] = (br[m]-mu3)*rin3*w0[m] + b0[m];
        o1[m] = (bi[m]-mu3)*rin3*w1[m] + b1[m];
    }
    store4bf(x2 + base + j0, o0);
    store4bf(x2 + base + 1024 + j0, o1);
}

// ---------- cross-attention over K=16 gist tokens: wave per (b,t) ----------
// KV combined: row (b*16+k) has Kh at [0,2048), V at [2048,4096)
__global__ __launch_bounds__(256) void attn_kernel(
    const u16* __restrict__ Q, const u16* __restrict__ KV,
    u16* __restrict__ ctx)
{
    const int wv = threadIdx.x >> 6;
    const int lane = threadIdx.x & 63;
    const int tg = blockIdx.x * 4 + wv;     // 0..8191
    const int b = tg >> 11;
    const size_t base = (size_t)tg * 2048 + lane * 32;

    float q[32];
    #pragma unroll
    for (int c = 0; c < 4; ++c)
        unpack8(*reinterpret_cast<const uint4*>(Q + base + c*8), &q[c*8]);

    float sc[16];
    #pragma unroll
    for (int k = 0; k < 16; ++k) {
        const u16* kr = KV + (size_t)(b*16 + k) * 4096 + lane*32;
        float p = 0.f;
        #pragma unroll
        for (int c = 0; c < 4; ++c) {
            float kv8[8]; unpack8(*reinterpret_cast<const uint4*>(kr + c*8), kv8);
            #pragma unroll
            for (int e = 0; e < 8; ++e) p += q[c*8+e] * kv8[e];
        }
        sc[k] = p;
    }
    #pragma unroll
    for (int k = 0; k < 16; ++k) {
        sc[k] += __shfl_xor(sc[k], 1, 64);
        sc[k] += __shfl_xor(sc[k], 2, 64);
        sc[k] *= 0.08838834764831845f;   // 1/sqrt(128)
    }
    float m = sc[0];
    #pragma unroll
    for (int k = 1; k < 16; ++k) m = fmaxf(m, sc[k]);
    float sum = 0.f;
    #pragma unroll
    for (int k = 0; k < 16; ++k) { sc[k] = expf(sc[k]-m); sum += sc[k]; }
    const float inv = 1.f / sum;

    float o[32];
    #pragma unroll
    for (int e = 0; e < 32; ++e) o[e] = 0.f;
    #pragma unroll
    for (int k = 0; k < 16; ++k) {
        const float p = sc[k] * inv;
        const u16* vr = KV + (size_t)(b*16 + k) * 4096 + 2048 + lane*32;
        #pragma unroll
        for (int c = 0; c < 4; ++c) {
            float v8[8]; unpack8(*reinterpret_cast<const uint4*>(vr + c*8), v8);
            #pragma unroll
            for (int e = 0; e < 8; ++e) o[c*8+e] += p * v8[e];
        }
    }
    #pragma unroll
    for (int c = 0; c < 4; ++c) {
        uint4 st = { pack2(o[c*8+0],o[c*8+1]), pack2(o[c*8+2],o[c*8+3]),
                     pack2(o[c*8+4],o[c*8+5]), pack2(o[c*8+6],o[c*8+7]) };
        *reinterpret_cast<uint4*>(ctx + base + c*8) = st;
    }
}

// ---------- MFMA GEMM, fragment-ordered LDS (zero bank conflicts) ----------
// C = A(MxK,bf16) * B(NxK,bf16)^T [+addf(fp32) +addb(bf16) +biasN(fp32)]
// LDS: 8 A-subtiles + 8 B-subtiles, each 16 rows x 32 cols stored in MFMA
// fragment-lane order (lane ln holds row=ln&15, kchunk=ln>>4). Staging DMA
// fetches per-lane exactly that fragment, so ds_read_b128 at lane*16 is
// sequential across lanes -> conflict-free. Global footprint per issue is
// unchanged (16 rows x 64B, lane-permuted) -> same coalescing.
#define BM 128
#define BN 128
#define BK 32

template<int OUTF32>
__global__ __launch_bounds__(256) void gemm_bt_kernel(
    const u16* __restrict__ A, const u16* __restrict__ B,
    void* __restrict__ Cv, const float* __restrict__ addf,
    const u16* __restrict__ addb, const float* __restrict__ biasN,
    int M, int N, int K)
{
    __shared__ u16 As[8*512];   // 8 subtiles x 1024B
    __shared__ u16 Bs[8*512];

    const int tid = threadIdx.x;
    const int lane = tid & 63;
    const int wave = tid >> 6;       // 0..3
    const int wm = wave >> 1;        // 0..1
    const int wn = wave & 1;         // 0..1
    const int row0 = blockIdx.y * BM;
    const int col0 = blockIdx.x * BN;

    frag_cd acc[4][4] = {};

    const int fr = lane & 15;        // fragment row within subtile
    const int fq = (lane >> 4) * 8;  // k-chunk start (elems)
    const int s0 = wave, s1 = wave + 4;   // this wave's staging subtiles

    for (int kt = 0; kt < K; kt += BK) {
        __syncthreads();   // previous tile's ds_reads must finish before overwrite
        {
            int ra0 = row0 + s0*16 + fr; if (ra0 >= M) ra0 = M - 1;
            int ra1 = row0 + s1*16 + fr; if (ra1 >= M) ra1 = M - 1;
            gld16(A + (size_t)ra0 * K + kt + fq, &As[s0*512]);
            gld16(A + (size_t)ra1 * K + kt + fq, &As[s1*512]);
            gld16(B + (size_t)(col0 + s0*16 + fr) * K + kt + fq, &Bs[s0*512]);
            gld16(B + (size_t)(col0 + s1*16 + fr) * K + kt + fq, &Bs[s1*512]);
        }
        __syncthreads();   // drain DMA before fragment reads

        frag_ab af[4], bf_[4];
        #pragma unroll
        for (int i = 0; i < 4; ++i)
            af[i] = *reinterpret_cast<const frag_ab*>(&As[(wm*4 + i)*512 + lane*8]);
        #pragma unroll
        for (int j = 0; j < 4; ++j)
            bf_[j] = *reinterpret_cast<const frag_ab*>(&Bs[(wn*4 + j)*512 + lane*8]);
        #pragma unroll
        for (int i = 0; i < 4; ++i)
            #pragma unroll
            for (int j = 0; j < 4; ++j)
                acc[i][j] = __builtin_amdgcn_mfma_f32_16x16x32_bf16(af[i], bf_[j], acc[i][j], 0, 0, 0);
    }

    #pragma unroll
    for (int i = 0; i < 4; ++i) {
        #pragma unroll
        for (int j = 0; j < 4; ++j) {
            #pragma unroll
            for (int r = 0; r < 4; ++r) {
                const int grow = row0 + wm*64 + i*16 + (lane >> 4) * 4 + r;
                const int gcol = col0 + wn*64 + j*16 + (lane & 15);
                if (grow < M) {
                    const size_t idx = (size_t)grow * N + gcol;
                    float v = acc[i][j][r];
                    if (addf) v += addf[idx];
                    if (addb) v += bf2f(addb[idx]);
                    if (biasN) v += biasN[gcol];
                    if (OUTF32) reinterpret_cast<float*>(Cv)[idx] = v;
                    else        reinterpret_cast<u16*>(Cv)[idx] = f2bf(v);
                }
            }
        }
    }
}

// ---------- launch ----------
extern "C" void kernel_launch(void* const* d_in, const int* in_sizes, int n_in,
                              void* d_out, int out_size, void* d_ws, size_t ws_size,
                              hipStream_t stream)
{
    const float* x          = (const float*)d_in[0];
    const float* gist_theta = (const float*)d_in[1];
    const float* gist_mag   = (const float*)d_in[2];
    const float* gist_wts   = (const float*)d_in[3];
    const float* ln_sheaf_w = (const float*)d_in[4];
    const float* ln_sheaf_b = (const float*)d_in[5];
    const float* sheaf_th   = (const float*)d_in[6];
    const float* alpha      = (const float*)d_in[7];
    const float* corr_W     = (const float*)d_in[8];
    const float* ln_gist_w  = (const float*)d_in[9];
    const float* ln_gist_b  = (const float*)d_in[10];
    const float* strength   = (const float*)d_in[11];
    const float* gr_w       = (const float*)d_in[12];
    const float* gr_b       = (const float*)d_in[13];
    const float* gca_w      = (const float*)d_in[14];
    const float* gca_b      = (const float*)d_in[15];
    const float* Wq         = (const float*)d_in[16];
    const float* Wk         = (const float*)d_in[17];
    const float* Wv         = (const float*)d_in[18];
    const float* Wo         = (const float*)d_in[19];
    const float* up_W       = (const float*)d_in[20];
    const float* up_b       = (const float*)d_in[21];
    float* out = (float*)d_out;

    char* w = (char*)d_ws;
    const size_t BIG = (size_t)4 * 2048 * 2048 * sizeof(u16);  // 33.5 MB
    u16* wA = (u16*)(w);                 // x1 -> xA -> x2(in-place) -> ctx
    u16* wB = (u16*)(w + BIG);           // WkWv(16.8MB) -> pre -> Q
    u16* wC = (u16*)(w + 2*BIG);         // Abuf(pad) -> xB
    u16* wslot = (u16*)(w + 3*BIG);      // Bbuf(pad) / single bf16 weight (8.4 MB)
    char* small = w + 3*BIG + (size_t)2048*2048*sizeof(u16);
    float* sheaf_cs = (float*)(small);
    float* gist_cs  = (float*)(small + 32768);
    u16* repr = (u16*)(small + 65536);            // 64x2048 bf16 (256 KB)
    u16* KV   = repr + 64*2048;                   // 64x4096 bf16 (512 KB)

    const int W4 = 2048*2048/4;   // float4 groups per weight matrix
    const dim3 gBig(16, 64), gKV(32, 1), gRepr(16, 1);

    setup_kernel<<<8, 256, 0, stream>>>(sheaf_th, gist_theta, gist_mag, gist_wts,
                                        strength, sheaf_cs, gist_cs);

    // gist_repr = concat(theta,mag) @ up_W^T + up_b   (K padded to 1056)
    apad_kernel<<<64, 256, 0, stream>>>(gist_theta, gist_mag, wC);
    wpad_kernel<<<2048, 256, 0, stream>>>(up_W, wslot);
    gemm_bt_kernel<0><<<gRepr, 256, 0, stream>>>(wC, wslot, repr, nullptr, nullptr, up_b,
                                                 64, 2048, 1056);

    // KV = repr @ [Wk;Wv]^T  (one N=4096 GEMM; WkWv staged bf16 in wB)
    convert_kernel<<<4096, 256, 0, stream>>>(Wk, wB, W4);
    convert_kernel<<<4096, 256, 0, stream>>>(Wv, wB + (size_t)2048*2048, W4);
    gemm_bt_kernel<0><<<gKV, 256, 0, stream>>>(repr, wB, KV, nullptr, nullptr, nullptr,
                                               64, 4096, 2048);

    ln_kernel<<<8192, 256, 0, stream>>>(x, ln_sheaf_w, ln_sheaf_b, wA);        // x1
    sheaf_kernel<<<8192, 256, 0, stream>>>(wA, sheaf_cs, alpha, wB);           // pre

    convert_kernel<<<4096, 256, 0, stream>>>(corr_W, wslot, W4);
    gemm_bt_kernel<0><<<gBig, 256, 0, stream>>>(wB, wslot, wA, x, wB, nullptr,
                                                8192, 2048, 2048);             // xA = x + pre + pre@corr^T
    stage2_kernel<<<8192, 256, 0, stream>>>(wA, gist_cs, ln_gist_w, ln_gist_b,
                                            gr_w, gr_b, gca_w, gca_b,
                                            wC, wA);                           // xB, x2
    convert_kernel<<<4096, 256, 0, stream>>>(Wq, wslot, W4);
    gemm_bt_kernel<0><<<gBig, 256, 0, stream>>>(wA, wslot, wB, nullptr, nullptr, nullptr,
                                                8192, 2048, 2048);             // Q
    attn_kernel<<<2048, 256, 0, stream>>>(wB, KV, wA);                         // ctx
    convert_kernel<<<4096, 256, 0, stream>>>(Wo, wslot, W4);
    gemm_bt_kernel<1><<<gBig, 256, 0, stream>>>(wA, wslot, (void*)out, nullptr, wC, nullptr,
                                                8192, 2048, 2048);             // out = xB + ctx@Wo^T
}

// Round 5
// 869.939 us; speedup vs baseline: 1.2178x; 1.2178x over previous
//
#include <hip/hip_runtime.h>
#include <hip/hip_bf16.h>

typedef unsigned short u16;
typedef unsigned int   u32;

using frag_ab = __attribute__((ext_vector_type(8))) short;  // 8 bf16
using frag_cd = __attribute__((ext_vector_type(4))) float;  // 4 fp32

// ---------- bf16 helpers ----------
__device__ __forceinline__ float bf2f(u16 u) {
    union { u32 i; float f; } v; v.i = ((u32)u) << 16; return v.f;
}
__device__ __forceinline__ u16 f2bf(float f) {
    __hip_bfloat16 h = __float2bfloat16(f);
    u16 u; __builtin_memcpy(&u, &h, 2); return u;
}
__device__ __forceinline__ float lo2f(u32 u) { union { u32 i; float f; } v; v.i = u << 16; return v.f; }
__device__ __forceinline__ float hi2f(u32 u) { union { u32 i; float f; } v; v.i = u & 0xffff0000u; return v.f; }
__device__ __forceinline__ void unpack8(uint4 v, float* f) {
    f[0]=lo2f(v.x); f[1]=hi2f(v.x); f[2]=lo2f(v.y); f[3]=hi2f(v.y);
    f[4]=lo2f(v.z); f[5]=hi2f(v.z); f[6]=lo2f(v.w); f[7]=hi2f(v.w);
}
__device__ __forceinline__ void load4f(const u16* p, float* f) {
    ushort4 v = *reinterpret_cast<const ushort4*>(p);
    f[0]=bf2f(v.x); f[1]=bf2f(v.y); f[2]=bf2f(v.z); f[3]=bf2f(v.w);
}
__device__ __forceinline__ void store4bf(u16* p, const float* f) {
    ushort4 v; v.x=f2bf(f[0]); v.y=f2bf(f[1]); v.z=f2bf(f[2]); v.w=f2bf(f[3]);
    *reinterpret_cast<ushort4*>(p) = v;
}
__device__ __forceinline__ u32 pack2(float a, float b) {
    return (u32)f2bf(a) | ((u32)f2bf(b) << 16);
}

// async global->LDS DMA, 16B per lane; lds dest = wave-uniform base + lane*16
__device__ __forceinline__ void gld16(const u16* g, u16* l) {
    __builtin_amdgcn_global_load_lds(
        (const __attribute__((address_space(1))) u32*)g,
        (__attribute__((address_space(3))) u32*)l, 16, 0, 0);
}

// ---------- block reduction (256 threads = 4 waves) ----------
__device__ __forceinline__ void block_reduce2(float& s, float& ss, float* red) {
    #pragma unroll
    for (int off = 32; off > 0; off >>= 1) {
        s  += __shfl_down(s, off, 64);
        ss += __shfl_down(ss, off, 64);
    }
    int wv = threadIdx.x >> 6, ln = threadIdx.x & 63;
    if (ln == 0) { red[wv*2] = s; red[wv*2+1] = ss; }
    __syncthreads();
    s  = red[0] + red[2] + red[4] + red[6];
    ss = red[1] + red[3] + red[5] + red[7];
    __syncthreads();
}

// ---------- fp32 -> bf16 conversion (n4 = n/4 float4 groups) ----------
__global__ __launch_bounds__(256) void convert_kernel(
    const float* __restrict__ in, u16* __restrict__ out, int n4)
{
    int i = blockIdx.x * 256 + threadIdx.x;
    if (i < n4) {
        float4 v = reinterpret_cast<const float4*>(in)[i];
        ushort4 o; o.x=f2bf(v.x); o.y=f2bf(v.y); o.z=f2bf(v.z); o.w=f2bf(v.w);
        reinterpret_cast<ushort4*>(out)[i] = o;
    }
}

// ---------- pad concat(theta,mag) -> Abuf (64 x 1056 bf16) ----------
__global__ __launch_bounds__(256) void apad_kernel(
    const float* __restrict__ gth, const float* __restrict__ gmag,
    u16* __restrict__ Abuf)
{
    const int r = blockIdx.x;             // 0..63
    const int tid = threadIdx.x;
    for (int c0 = tid*4; c0 < 1056; c0 += 1024) {
        float f[4];
        #pragma unroll
        for (int i = 0; i < 4; ++i) {
            int c = c0 + i;
            f[i] = (c < 1024) ? gth[(size_t)r*1024 + c] : (c == 1024 ? gmag[r] : 0.f);
        }
        store4bf(Abuf + (size_t)r*1056 + c0, f);
    }
}

// ---------- pad up_W (2048 x 1025 fp32) -> Bbuf (2048 x 1056 bf16) ----------
__global__ __launch_bounds__(256) void wpad_kernel(
    const float* __restrict__ upW, u16* __restrict__ Bbuf)
{
    const int r = blockIdx.x;             // 0..2047
    const int tid = threadIdx.x;
    for (int c0 = tid*4; c0 < 1056; c0 += 1024) {
        float f[4];
        #pragma unroll
        for (int i = 0; i < 4; ++i) {
            int c = c0 + i;
            f[i] = (c < 1025) ? upW[(size_t)r*1025 + c] : 0.f;
        }
        store4bf(Bbuf + (size_t)r*1056 + c0, f);
    }
}

// ---------- setup: cos/sin tables ----------
__global__ __launch_bounds__(256) void setup_kernel(
    const float* __restrict__ sheaf_th, const float* __restrict__ gth,
    const float* __restrict__ gmag, const float* __restrict__ gwts,
    const float* __restrict__ strength, float* __restrict__ sheaf_cs,
    float* __restrict__ gist_cs)
{
    int bx = blockIdx.x, tid = threadIdx.x;
    if (bx < 4) {
        for (int j = tid; j < 1024; j += 256) {
            float th = sheaf_th[bx*1024 + j];
            sheaf_cs[bx*1024 + j]        = cosf(th);
            sheaf_cs[4096 + bx*1024 + j] = sinf(th);
        }
    } else {
        int b = bx - 4;
        float w[16], wsum = 0.f;
        #pragma unroll
        for (int k = 0; k < 16; ++k) {
            w[k] = gwts[b*16+k] * gmag[b*16+k];
            wsum += w[k];
        }
        float inv = 1.f / (wsum + 1e-8f);
        float sig = 1.f / (1.f + expf(-strength[0]));
        for (int j = tid; j < 1024; j += 256) {
            float th = 0.f;
            #pragma unroll
            for (int k = 0; k < 16; ++k)
                th += w[k] * inv * gth[(size_t)(b*16+k)*1024 + j];
            th *= sig;
            gist_cs[b*1024 + j]        = cosf(th);
            gist_cs[4096 + b*1024 + j] = sinf(th);
        }
    }
}

// ---------- LN over rows of 2048: fp32 in -> bf16 out ----------
__global__ __launch_bounds__(256) void ln_kernel(
    const float* __restrict__ in, const float* __restrict__ w,
    const float* __restrict__ b, u16* __restrict__ out)
{
    __shared__ float red[8];
    const size_t base = (size_t)blockIdx.x * 2048;
    const int e0 = threadIdx.x * 8;
    float x[8];
    *reinterpret_cast<float4*>(&x[0]) = *reinterpret_cast<const float4*>(in + base + e0);
    *reinterpret_cast<float4*>(&x[4]) = *reinterpret_cast<const float4*>(in + base + e0 + 4);
    float s = 0.f, ss = 0.f;
    #pragma unroll
    for (int i = 0; i < 8; ++i) { s += x[i]; ss += x[i]*x[i]; }
    block_reduce2(s, ss, red);
    const float mu = s * (1.f/2048.f);
    const float rin = rsqrtf(ss * (1.f/2048.f) - mu*mu + 1e-5f);
    float wv[8], bv[8];
    *reinterpret_cast<float4*>(&wv[0]) = *reinterpret_cast<const float4*>(w + e0);
    *reinterpret_cast<float4*>(&wv[4]) = *reinterpret_cast<const float4*>(w + e0 + 4);
    *reinterpret_cast<float4*>(&bv[0]) = *reinterpret_cast<const float4*>(b + e0);
    *reinterpret_cast<float4*>(&bv[4]) = *reinterpret_cast<const float4*>(b + e0 + 4);
    float o[8];
    #pragma unroll
    for (int i = 0; i < 8; ++i) o[i] = (x[i]-mu)*rin*wv[i] + bv[i];
    uint4 st = { pack2(o[0],o[1]), pack2(o[2],o[3]), pack2(o[4],o[5]), pack2(o[6],o[7]) };
    *reinterpret_cast<uint4*>(out + base + e0) = st;
}

// ---------- sheaf: pre = x1 - |alpha| * (4*x1 - sum rot_inv(shift(x1))) ----------
__global__ __launch_bounds__(256) void sheaf_kernel(
    const u16* __restrict__ x1, const float* __restrict__ scs,
    const float* __restrict__ alpha_p, u16* __restrict__ pre)
{
    const int row = blockIdx.x;
    const int t = row & 2047;
    const int j0 = threadIdx.x * 4;
    const size_t base = (size_t)row * 2048;
    const float a = fabsf(alpha_p[0]);

    float xr[4], xi[4];
    load4f(x1 + base + j0, xr);
    load4f(x1 + base + 1024 + j0, xi);
    float lr[4], li[4];
    #pragma unroll
    for (int m = 0; m < 4; ++m) { lr[m] = 4.f*xr[m]; li[m] = 4.f*xi[m]; }

    #pragma unroll
    for (int idx = 0; idx < 4; ++idx) {
        const int sh = 3 - idx;
        if (t >= sh) {
            const float4 c4 = *reinterpret_cast<const float4*>(&scs[idx*1024 + j0]);
            const float4 s4 = *reinterpret_cast<const float4*>(&scs[4096 + idx*1024 + j0]);
            float c[4] = {c4.x, c4.y, c4.z, c4.w};
            float sn[4] = {s4.x, s4.y, s4.z, s4.w};
            float yr[4], yi[4];
            load4f(x1 + base - (size_t)sh*2048 + j0, yr);
            load4f(x1 + base - (size_t)sh*2048 + 1024 + j0, yi);
            #pragma unroll
            for (int m = 0; m < 4; ++m) {
                lr[m] -= yr[m]*c[m] + yi[m]*sn[m];     // rot_inv real
                li[m] -= yi[m]*c[m] - yr[m]*sn[m];     // rot_inv imag
            }
        }
    }
    float pr[4], pi[4];
    #pragma unroll
    for (int m = 0; m < 4; ++m) { pr[m] = xr[m] - a*lr[m]; pi[m] = xi[m] - a*li[m]; }
    store4bf(pre + base + j0, pr);
    store4bf(pre + base + 1024 + j0, pi);
}

// ---------- stage2: xn=LN(xA); g=LN(rot(xn)); xB=xA-xn+g; x2=LN(xB) ----------
__global__ __launch_bounds__(256) void stage2_kernel(
    const u16* __restrict__ xA, const float* __restrict__ gcs,
    const float* __restrict__ lgw, const float* __restrict__ lgb,
    const float* __restrict__ grw, const float* __restrict__ grb,
    const float* __restrict__ gcaw, const float* __restrict__ gcab,
    u16* __restrict__ xB, u16* __restrict__ x2)
{
    __shared__ float red[8];
    const int row = blockIdx.x;
    const int b = row >> 11;
    const int j0 = threadIdx.x * 4;
    const size_t base = (size_t)row * 2048;

    float ar[4], ai[4];
    load4f(xA + base + j0, ar);
    load4f(xA + base + 1024 + j0, ai);

    float s = 0.f, ss = 0.f;
    #pragma unroll
    for (int m = 0; m < 4; ++m) { s += ar[m]+ai[m]; ss += ar[m]*ar[m] + ai[m]*ai[m]; }
    block_reduce2(s, ss, red);
    float mu = s * (1.f/2048.f);
    float rin = rsqrtf(ss * (1.f/2048.f) - mu*mu + 1e-5f);

    float w0[4], b0[4], w1[4], b1[4];
    *reinterpret_cast<float4*>(w0) = *reinterpret_cast<const float4*>(lgw + j0);
    *reinterpret_cast<float4*>(b0) = *reinterpret_cast<const float4*>(lgb + j0);
    *reinterpret_cast<float4*>(w1) = *reinterpret_cast<const float4*>(lgw + 1024 + j0);
    *reinterpret_cast<float4*>(b1) = *reinterpret_cast<const float4*>(lgb + 1024 + j0);
    float xnr[4], xni[4];
    #pragma unroll
    for (int m = 0; m < 4; ++m) {
        xnr[m] = (ar[m]-mu)*rin*w0[m] + b0[m];
        xni[m] = (ai[m]-mu)*rin*w1[m] + b1[m];
    }

    const float4 c4 = *reinterpret_cast<const float4*>(&gcs[b*1024 + j0]);
    const float4 s4 = *reinterpret_cast<const float4*>(&gcs[4096 + b*1024 + j0]);
    float c[4] = {c4.x, c4.y, c4.z, c4.w};
    float sn[4] = {s4.x, s4.y, s4.z, s4.w};
    float rr[4], ri[4];
    #pragma unroll
    for (int m = 0; m < 4; ++m) {
        rr[m] = xnr[m]*c[m] - xni[m]*sn[m];
        ri[m] = xnr[m]*sn[m] + xni[m]*c[m];
    }

    s = 0.f; ss = 0.f;
    #pragma unroll
    for (int m = 0; m < 4; ++m) { s += rr[m]+ri[m]; ss += rr[m]*rr[m] + ri[m]*ri[m]; }
    block_reduce2(s, ss, red);
    float mu2 = s * (1.f/2048.f);
    float rin2 = rsqrtf(ss * (1.f/2048.f) - mu2*mu2 + 1e-5f);

    *reinterpret_cast<float4*>(w0) = *reinterpret_cast<const float4*>(grw + j0);
    *reinterpret_cast<float4*>(b0) = *reinterpret_cast<const float4*>(grb + j0);
    *reinterpret_cast<float4*>(w1) = *reinterpret_cast<const float4*>(grw + 1024 + j0);
    *reinterpret_cast<float4*>(b1) = *reinterpret_cast<const float4*>(grb + 1024 + j0);
    float br[4], bi[4];
    #pragma unroll
    for (int m = 0; m < 4; ++m) {
        float gr_ = (rr[m]-mu2)*rin2*w0[m] + b0[m];
        float gi_ = (ri[m]-mu2)*rin2*w1[m] + b1[m];
        br[m] = ar[m] - xnr[m] + gr_;
        bi[m] = ai[m] - xni[m] + gi_;
    }
    store4bf(xB + base + j0, br);
    store4bf(xB + base + 1024 + j0, bi);

    s = 0.f; ss = 0.f;
    #pragma unroll
    for (int m = 0; m < 4; ++m) { s += br[m]+bi[m]; ss += br[m]*br[m] + bi[m]*bi[m]; }
    block_reduce2(s, ss, red);
    float mu3 = s * (1.f/2048.f);
    float rin3 = rsqrtf(ss * (1.f/2048.f) - mu3*mu3 + 1e-5f);

    *reinterpret_cast<float4*>(w0) = *reinterpret_cast<const float4*>(gcaw + j0);
    *reinterpret_cast<float4*>(b0) = *reinterpret_cast<const float4*>(gcab + j0);
    *reinterpret_cast<float4*>(w1) = *reinterpret_cast<const float4*>(gcaw + 1024 + j0);
    *reinterpret_cast<float4*>(b1) = *reinterpret_cast<const float4*>(gcab + 1024 + j0);
    float o0[4], o1[4];
    #pragma unroll
    for (int m = 0; m < 4; ++m) {
        o0[m] = (br[m]-mu3)*rin3*w0[m] + b0[m];
        o1[m] = (bi[m]-mu3)*rin3*w1[m] + b1[m];
    }
    store4bf(x2 + base + j0, o0);
    store4bf(x2 + base + 1024 + j0, o1);
}

// ---------- cross-attention over K=16 gist tokens: wave per (b,t) ----------
// KV combined: row (b*16+k) has Kh at [0,2048), V at [2048,4096)
__global__ __launch_bounds__(256) void attn_kernel(
    const u16* __restrict__ Q, const u16* __restrict__ KV,
    u16* __restrict__ ctx)
{
    const int wv = threadIdx.x >> 6;
    const int lane = threadIdx.x & 63;
    const int tg = blockIdx.x * 4 + wv;     // 0..8191
    const int b = tg >> 11;
    const size_t base = (size_t)tg * 2048 + lane * 32;

    float q[32];
    #pragma unroll
    for (int c = 0; c < 4; ++c)
        unpack8(*reinterpret_cast<const uint4*>(Q + base + c*8), &q[c*8]);

    float sc[16];
    #pragma unroll
    for (int k = 0; k < 16; ++k) {
        const u16* kr = KV + (size_t)(b*16 + k) * 4096 + lane*32;
        float p = 0.f;
        #pragma unroll
        for (int c = 0; c < 4; ++c) {
            float kv8[8]; unpack8(*reinterpret_cast<const uint4*>(kr + c*8), kv8);
            #pragma unroll
            for (int e = 0; e < 8; ++e) p += q[c*8+e] * kv8[e];
        }
        sc[k] = p;
    }
    #pragma unroll
    for (int k = 0; k < 16; ++k) {
        sc[k] += __shfl_xor(sc[k], 1, 64);
        sc[k] += __shfl_xor(sc[k], 2, 64);
        sc[k] *= 0.08838834764831845f;   // 1/sqrt(128)
    }
    float m = sc[0];
    #pragma unroll
    for (int k = 1; k < 16; ++k) m = fmaxf(m, sc[k]);
    float sum = 0.f;
    #pragma unroll
    for (int k = 0; k < 16; ++k) { sc[k] = expf(sc[k]-m); sum += sc[k]; }
    const float inv = 1.f / sum;

    float o[32];
    #pragma unroll
    for (int e = 0; e < 32; ++e) o[e] = 0.f;
    #pragma unroll
    for (int k = 0; k < 16; ++k) {
        const float p = sc[k] * inv;
        const u16* vr = KV + (size_t)(b*16 + k) * 4096 + 2048 + lane*32;
        #pragma unroll
        for (int c = 0; c < 4; ++c) {
            float v8[8]; unpack8(*reinterpret_cast<const uint4*>(vr + c*8), v8);
            #pragma unroll
            for (int e = 0; e < 8; ++e) o[c*8+e] += p * v8[e];
        }
    }
    #pragma unroll
    for (int c = 0; c < 4; ++c) {
        uint4 st = { pack2(o[c*8+0],o[c*8+1]), pack2(o[c*8+2],o[c*8+3]),
                     pack2(o[c*8+4],o[c*8+5]), pack2(o[c*8+6],o[c*8+7]) };
        *reinterpret_cast<uint4*>(ctx + base + c*8) = st;
    }
}

// ---------- MFMA GEMM, XOR-swizzled LDS staging ----------
// C = A(MxK,bf16) * B(NxK,bf16)^T [+addf(fp32) +addb(bf16) +biasN(fp32)]
// Each 16-row x 64-B subtile is one wave gld16 issue: lane j fetches
// (row=j>>2, chunk=(j&3)^((j>>3)&3)) -> 4 consecutive lanes cover one
// contiguous 64B row segment (full coalescing), and data (fr,fq) lands at
// slot 4*fr + (fq ^ ((fr>>1)&3)), whose fragment-read addresses are
// bank-conflict-free for every aligned 8-lane group (enumerated).
#define BM 128
#define BN 128
#define BK 32

template<int OUTF32>
__global__ __launch_bounds__(256) void gemm_bt_kernel(
    const u16* __restrict__ A, const u16* __restrict__ B,
    void* __restrict__ Cv, const float* __restrict__ addf,
    const u16* __restrict__ addb, const float* __restrict__ biasN,
    int M, int N, int K)
{
    __shared__ u16 As[8*512];   // 8 subtiles x 1024B, subtile s at [s*512]
    __shared__ u16 Bs[8*512];

    const int tid = threadIdx.x;
    const int lane = tid & 63;
    const int wave = tid >> 6;       // 0..3
    const int wm = wave >> 1;        // 0..1
    const int wn = wave & 1;         // 0..1
    const int row0 = blockIdx.y * BM;
    const int col0 = blockIdx.x * BN;

    frag_cd acc[4][4] = {};

    // staging lane mapping (swizzled)
    const int srow   = lane >> 2;                        // 0..15
    const int schunk = (lane & 3) ^ ((lane >> 3) & 3);   // 0..3
    const int scol   = schunk * 8;                       // elems
    const int s0 = wave, s1 = wave + 4;                  // this wave's subtiles

    // fragment read slot (u16 offset within subtile), loop-invariant
    const int fr = lane & 15;
    const int fq8 = lane >> 4;
    const int fslot = (4*fr + (fq8 ^ ((fr >> 1) & 3))) * 8;

    for (int kt = 0; kt < K; kt += BK) {
        __syncthreads();   // previous tile's ds_reads must finish before overwrite
        {
            int ra0 = row0 + s0*16 + srow; if (ra0 >= M) ra0 = M - 1;
            int ra1 = row0 + s1*16 + srow; if (ra1 >= M) ra1 = M - 1;
            gld16(A + (size_t)ra0 * K + kt + scol, &As[s0*512]);
            gld16(A + (size_t)ra1 * K + kt + scol, &As[s1*512]);
            gld16(B + (size_t)(col0 + s0*16 + srow) * K + kt + scol, &Bs[s0*512]);
            gld16(B + (size_t)(col0 + s1*16 + srow) * K + kt + scol, &Bs[s1*512]);
        }
        __syncthreads();   // drain DMA before fragment reads

        frag_ab af[4], bf_[4];
        #pragma unroll
        for (int i = 0; i < 4; ++i)
            af[i] = *reinterpret_cast<const frag_ab*>(&As[(wm*4 + i)*512 + fslot]);
        #pragma unroll
        for (int j = 0; j < 4; ++j)
            bf_[j] = *reinterpret_cast<const frag_ab*>(&Bs[(wn*4 + j)*512 + fslot]);
        #pragma unroll
        for (int i = 0; i < 4; ++i)
            #pragma unroll
            for (int j = 0; j < 4; ++j)
                acc[i][j] = __builtin_amdgcn_mfma_f32_16x16x32_bf16(af[i], bf_[j], acc[i][j], 0, 0, 0);
    }

    #pragma unroll
    for (int i = 0; i < 4; ++i) {
        #pragma unroll
        for (int j = 0; j < 4; ++j) {
            #pragma unroll
            for (int r = 0; r < 4; ++r) {
                const int grow = row0 + wm*64 + i*16 + (lane >> 4) * 4 + r;
                const int gcol = col0 + wn*64 + j*16 + (lane & 15);
                if (grow < M) {
                    const size_t idx = (size_t)grow * N + gcol;
                    float v = acc[i][j][r];
                    if (addf) v += addf[idx];
                    if (addb) v += bf2f(addb[idx]);
                    if (biasN) v += biasN[gcol];
                    if (OUTF32) reinterpret_cast<float*>(Cv)[idx] = v;
                    else        reinterpret_cast<u16*>(Cv)[idx] = f2bf(v);
                }
            }
        }
    }
}

// ---------- launch ----------
extern "C" void kernel_launch(void* const* d_in, const int* in_sizes, int n_in,
                              void* d_out, int out_size, void* d_ws, size_t ws_size,
                              hipStream_t stream)
{
    const float* x          = (const float*)d_in[0];
    const float* gist_theta = (const float*)d_in[1];
    const float* gist_mag   = (const float*)d_in[2];
    const float* gist_wts   = (const float*)d_in[3];
    const float* ln_sheaf_w = (const float*)d_in[4];
    const float* ln_sheaf_b = (const float*)d_in[5];
    const float* sheaf_th   = (const float*)d_in[6];
    const float* alpha      = (const float*)d_in[7];
    const float* corr_W     = (const float*)d_in[8];
    const float* ln_gist_w  = (const float*)d_in[9];
    const float* ln_gist_b  = (const float*)d_in[10];
    const float* strength   = (const float*)d_in[11];
    const float* gr_w       = (const float*)d_in[12];
    const float* gr_b       = (const float*)d_in[13];
    const float* gca_w      = (const float*)d_in[14];
    const float* gca_b      = (const float*)d_in[15];
    const float* Wq         = (const float*)d_in[16];
    const float* Wk         = (const float*)d_in[17];
    const float* Wv         = (const float*)d_in[18];
    const float* Wo         = (const float*)d_in[19];
    const float* up_W       = (const float*)d_in[20];
    const float* up_b       = (const float*)d_in[21];
    float* out = (float*)d_out;

    char* w = (char*)d_ws;
    const size_t BIG = (size_t)4 * 2048 * 2048 * sizeof(u16);  // 33.5 MB
    u16* wA = (u16*)(w);                 // x1 -> xA -> x2(in-place) -> ctx
    u16* wB = (u16*)(w + BIG);           // WkWv(16.8MB) -> pre -> Q
    u16* wC = (u16*)(w + 2*BIG);         // Abuf(pad) -> xB
    u16* wslot = (u16*)(w + 3*BIG);      // Bbuf(pad) / single bf16 weight (8.4 MB)
    char* small = w + 3*BIG + (size_t)2048*2048*sizeof(u16);
    float* sheaf_cs = (float*)(small);
    float* gist_cs  = (float*)(small + 32768);
    u16* repr = (u16*)(small + 65536);            // 64x2048 bf16 (256 KB)
    u16* KV   = repr + 64*2048;                   // 64x4096 bf16 (512 KB)

    const int W4 = 2048*2048/4;   // float4 groups per weight matrix
    const dim3 gBig(16, 64), gKV(32, 1), gRepr(16, 1);

    setup_kernel<<<8, 256, 0, stream>>>(sheaf_th, gist_theta, gist_mag, gist_wts,
                                        strength, sheaf_cs, gist_cs);

    // gist_repr = concat(theta,mag) @ up_W^T + up_b   (K padded to 1056)
    apad_kernel<<<64, 256, 0, stream>>>(gist_theta, gist_mag, wC);
    wpad_kernel<<<2048, 256, 0, stream>>>(up_W, wslot);
    gemm_bt_kernel<0><<<gRepr, 256, 0, stream>>>(wC, wslot, repr, nullptr, nullptr, up_b,
                                                 64, 2048, 1056);

    // KV = repr @ [Wk;Wv]^T  (one N=4096 GEMM; WkWv staged bf16 in wB)
    convert_kernel<<<4096, 256, 0, stream>>>(Wk, wB, W4);
    convert_kernel<<<4096, 256, 0, stream>>>(Wv, wB + (size_t)2048*2048, W4);
    gemm_bt_kernel<0><<<gKV, 256, 0, stream>>>(repr, wB, KV, nullptr, nullptr, nullptr,
                                               64, 4096, 2048);

    ln_kernel<<<8192, 256, 0, stream>>>(x, ln_sheaf_w, ln_sheaf_b, wA);        // x1
    sheaf_kernel<<<8192, 256, 0, stream>>>(wA, sheaf_cs, alpha, wB);           // pre

    convert_kernel<<<4096, 256, 0, stream>>>(corr_W, wslot, W4);
    gemm_bt_kernel<0><<<gBig, 256, 0, stream>>>(wB, wslot, wA, x, wB, nullptr,
                                                8192, 2048, 2048);             // xA = x + pre + pre@corr^T
    stage2_kernel<<<8192, 256, 0, stream>>>(wA, gist_cs, ln_gist_w, ln_gist_b,
                                            gr_w, gr_b, gca_w, gca_b,
                                            wC, wA);                           // xB, x2
    convert_kernel<<<4096, 256, 0, stream>>>(Wq, wslot, W4);
    gemm_bt_kernel<0><<<gBig, 256, 0, stream>>>(wA, wslot, wB, nullptr, nullptr, nullptr,
                                                8192, 2048, 2048);             // Q
    attn_kernel<<<2048, 256, 0, stream>>>(wB, KV, wA);                         // ctx
    convert_kernel<<<4096, 256, 0, stream>>>(Wo, wslot, W4);
    gemm_bt_kernel<1><<<gBig, 256, 0, stream>>>(wA, wslot, (void*)out, nullptr, wC, nullptr,
                                                8192, 2048, 2048);             // out = xB + ctx@Wo^T
}